// Round 8
// baseline (5686.935 us; speedup 1.0000x reference)
//
#include <hip/hip_runtime.h>
#include <hip/hip_bf16.h>
#include <stdint.h>

namespace {

constexpr int Tn = 512, In = 256, Hn = 256, Kn = 512;

typedef __attribute__((ext_vector_type(8))) short bf16x8;
typedef __attribute__((ext_vector_type(4))) float f32x4;
typedef __attribute__((ext_vector_type(4))) unsigned int u32x4;

__device__ __forceinline__ float sigmoidf_(float x) { return 1.f / (1.f + __expf(-x)); }
__device__ __forceinline__ float tanhf_(float x)    { return 2.f / (1.f + __expf(-2.f * x)) - 1.f; }

// A-tile chunk swizzle (R5-validated): kills 16-way ds conflicts in staging
__device__ __forceinline__ int swz(int c) { return c ^ ((c >> 4) & 15); }
// transpose-patch chunk swizzle (involution on [0,32))
__device__ __forceinline__ int swz16(int c) { return c ^ (((c >> 3) & 3) << 1); }

// scope-selected ops. loc=true: sc0 (same-XCD L2). loc=false: sc1 (LLC, R5-proven).
__device__ __forceinline__ void st16(void* p, bf16x8 v, bool loc) {
    if (loc) asm volatile("global_store_dwordx4 %0, %1, off sc0" :: "v"(p), "v"(v) : "memory");
    else     asm volatile("global_store_dwordx4 %0, %1, off sc1" :: "v"(p), "v"(v) : "memory");
}
__device__ __forceinline__ bf16x8 ld16(const void* p, bool loc) {
    bf16x8 r;
    if (loc) asm volatile("global_load_dwordx4 %0, %1, off sc0" : "=v"(r) : "v"(p) : "memory");
    else     asm volatile("global_load_dwordx4 %0, %1, off sc1" : "=v"(r) : "v"(p) : "memory");
    return r;
}
__device__ __forceinline__ u32x4 ldflags(const void* p, bool loc) {
    u32x4 r;
    if (loc) asm volatile("global_load_dwordx4 %0, %1, off sc0\n\ts_waitcnt vmcnt(0)"
                          : "=v"(r) : "v"(p) : "memory");
    else     asm volatile("global_load_dwordx4 %0, %1, off sc1\n\ts_waitcnt vmcnt(0)"
                          : "=v"(r) : "v"(p) : "memory");
    return r;
}
__device__ __forceinline__ void stdw(void* p, uint32_t v, bool loc) {
    if (loc) asm volatile("global_store_dword %0, %1, off sc0" :: "v"(p), "v"(v) : "memory");
    else     asm volatile("global_store_dword %0, %1, off sc1" :: "v"(p), "v"(v) : "memory");
}
__device__ __forceinline__ uint32_t lddw(const void* p, bool loc) {
    uint32_t r;
    if (loc) asm volatile("global_load_dword %0, %1, off sc0\n\ts_waitcnt vmcnt(0)"
                          : "=v"(r) : "v"(p) : "memory");
    else     asm volatile("global_load_dword %0, %1, off sc1\n\ts_waitcnt vmcnt(0)"
                          : "=v"(r) : "v"(p) : "memory");
    return r;
}

// ============================ FAST PATH =====================================
// 64 WGs: wg = cl + 16*j. Cluster cl owns batch [16cl,+16); member j owns units [64j,+64).
// 8 waves: w8 = ks*4 + wu. wu -> 16-unit sub-slice; ks -> K-half. Weights VGPR-resident.
// A-tile frag-linear LDS: chunk c = kb*64+lane, elem e = A[m=lane&15][kb*32+(lane>>4)*8+e].
// Barriers/step: B2 (A ready), B3 (partials ready), B4 (Tp ready for next import).

__global__ void pack_w_frag(const float* __restrict__ W, __hip_bfloat16* __restrict__ Wpf,
                            uint32_t* __restrict__ sync) {
    int idx  = blockIdx.x * 256 + threadIdx.x;
    int lane = idx & 63;
    int kb   = (idx >> 6) & 15;
    int nt2  = idx >> 10;
    int g = nt2 & 3, wu = (nt2 >> 2) & 3, jj = nt2 >> 4;
    int row = g * 256 + jj * 64 + wu * 16 + (lane & 15);
    int k0  = kb * 32 + (lane >> 4) * 8;
    const float* src = W + (size_t)row * Kn + k0;
    union { __hip_bfloat16 h[8]; bf16x8 v; } u;
#pragma unroll
    for (int e = 0; e < 8; ++e) u.h[e] = __float2bfloat16(src[e]);
    *(bf16x8*)(Wpf + (size_t)idx * 8) = u.v;
    // zero flags(256dw) + tokens(256dw) + votes(64dw) EVERY launch (graph replays
    // reuse ws; monotonic flags/token/vote state must restart at 0). Kernel-end
    // release flushes; next dispatch's acquire invalidates stale L2 copies.
    if (blockIdx.x == 0)
        for (int i = threadIdx.x; i < 576; i += 256) sync[i] = 0u;
}

__global__ __launch_bounds__(512, 2) void lstm_cluster(
    const float* __restrict__ X, const float* __restrict__ bias,
    const __hip_bfloat16* __restrict__ Wpf, __hip_bfloat16* __restrict__ hbuf,
    uint32_t* __restrict__ flags, uint32_t* __restrict__ tokens,
    uint32_t* __restrict__ votes, float* __restrict__ out)
{
    __shared__ bf16x8 AfrV[1024];      // 16 KB frag-linear A (x: 0..511, h: 512..1023)
    __shared__ f32x4 Red[4][4][64];    // 16 KB K-split partials
    __shared__ bf16x8 Tp[4][32];       // 2 KB per-gate-wave transpose patches
    __shared__ uint32_t locSh;

    const int tid = threadIdx.x, lane = tid & 63, w8 = tid >> 6;
    const int wu = w8 & 3, ks = w8 >> 2;
    const int l15 = lane & 15, lk = lane >> 4;
    const int wg = blockIdx.x, cl = wg & 15, j = wg >> 4;

    // ---- phase-1 token: publish over the sc0 channel ASAP ----
    if (tid == 0) stdw(tokens + wg * 4, 0x51000000u | (uint32_t)wg, true);

    // ---- resident weights: 32 frags / lane (takes a while; tokens propagate) ----
    bf16x8 wf[4][8];
#pragma unroll
    for (int g = 0; g < 4; ++g)
#pragma unroll
        for (int i = 0; i < 8; ++i) {
            const int nt2 = (j * 4 + wu) * 4 + g, kb = ks * 8 + i;
            wf[g][i] = *(const bf16x8*)(Wpf + ((size_t)(nt2 * 16 + kb) * 64 + lane) * 8);
        }
    float bg[4];
#pragma unroll
    for (int g = 0; g < 4; ++g) bg[g] = bias[g * 256 + j * 64 + wu * 16 + l15];

    // ---- empirical sc0-channel validation + unanimous consensus ----
    // (tokens are zeroed fresh each launch and the dispatch-begin acquire
    //  invalidates stale L2 lines, so a pass can only come from live stores)
    if (tid == 0) {
        uint32_t ok = 1;
        // phase 1: see mates' P1/P2 over sc0 -> co-located + store visible
#pragma unroll
        for (int m = 0; m < 4; ++m) {
            if (m == j) continue;
            const uint32_t want = (uint32_t)(cl + 16 * m);
            uint32_t v = 0;
            for (uint32_t g2 = 0; g2 < (1u << 14); ++g2) {
                v = lddw(tokens + (cl + 16 * m) * 4, true);
                if (((v >> 24) == 0x51u || (v >> 24) == 0x52u) && (v & 0xFFFFFFu) == want) break;
                v = 0;
            }
            if (v == 0) ok = 0;
        }
        // phase 2: UPDATE same address; mates must see the new value (catches
        // "sc0 load pinned on a cached copy")
        stdw(tokens + wg * 4, 0x52000000u | (uint32_t)wg, true);
#pragma unroll
        for (int m = 0; m < 4; ++m) {
            if (m == j) continue;
            const uint32_t want = (uint32_t)(cl + 16 * m);
            uint32_t v = 0;
            for (uint32_t g2 = 0; g2 < (1u << 14); ++g2) {
                v = lddw(tokens + (cl + 16 * m) * 4, true);
                if ((v >> 24) == 0x52u && (v & 0xFFFFFFu) == want) break;
                v = 0;
            }
            if (v == 0) ok = 0;
        }
        // consensus: publish vote via sc1 (always works); all must agree
        stdw(votes + wg, 1u + ok, false);
        asm volatile("s_waitcnt vmcnt(0)" ::: "memory");
        uint32_t allok = 1;
#pragma unroll
        for (int m = 0; m < 4; ++m) {
            uint32_t v = 0;
            for (uint32_t g2 = 0; g2 < (1u << 20); ++g2) {
                v = lddw(votes + (cl + 16 * m), false);
                if (v != 0) break;
            }
            if (v != 2u) allok = 0;
        }
        locSh = allok;
    }
    // zero A tile (h region must be zero at t=0)
    {
        const bf16x8 z = {};
        AfrV[tid] = z; AfrV[tid + 512] = z;
    }
    __syncthreads();
    const bool loc = (locSh != 0);

    float c4[4] = {0.f, 0.f, 0.f, 0.f};

    const float* xbase = X + (size_t)(cl * 16 + wu * 4 + lk) * Tn * In;
    float4 xp[4];
    if (ks == 0) {
#pragma unroll
        for (int cc = 0; cc < 2; ++cc) {
            const int o8 = l15 + cc * 16;
            xp[cc * 2]     = *(const float4*)(xbase + o8 * 8);
            xp[cc * 2 + 1] = *(const float4*)(xbase + o8 * 8 + 4);
        }
    }

#pragma unroll 1
    for (int t = 0; t < Tn; ++t) {
        // ---- ks==0: cvt prefetched x(t) -> A-x region ----
        if (ks == 0) {
            const int b = wu * 4 + lk;
#pragma unroll
            for (int cc = 0; cc < 2; ++cc) {
                const int o8 = l15 + cc * 16;
                union { __hip_bfloat16 h[8]; bf16x8 v; } u;
                u.h[0] = __float2bfloat16(xp[cc * 2].x); u.h[1] = __float2bfloat16(xp[cc * 2].y);
                u.h[2] = __float2bfloat16(xp[cc * 2].z); u.h[3] = __float2bfloat16(xp[cc * 2].w);
                u.h[4] = __float2bfloat16(xp[cc * 2 + 1].x); u.h[5] = __float2bfloat16(xp[cc * 2 + 1].y);
                u.h[6] = __float2bfloat16(xp[cc * 2 + 1].z); u.h[7] = __float2bfloat16(xp[cc * 2 + 1].w);
                AfrV[swz(b + 16 * o8)] = u.v;
            }
        }
        // ---- ks==1: import h(t) for member wu ----
        if (ks == 1 && t > 0) {
            if (wu == j) {
                // own member: h tile sits in this WG's Tp patches, written in the
                // gate phase of t-1; ORDERED BY B4 (end-of-loop barrier).
                const int o32 = lane >> 4;                       // unit octet 0..3
                const int cp  = (lane & 15) * 2 + (o32 & 1);
                const bf16x8 r0 = Tp[o32 >> 1][swz16(cp)];
                const bf16x8 r1 = Tp[2 + (o32 >> 1)][swz16(cp)];
                AfrV[swz(512 + wu * 128 + lane)]      = r0;
                AfrV[swz(512 + wu * 128 + lane + 64)] = r1;
            } else {
                const char* fl = (const char*)flags + (cl * 4 + wu) * 16;
                uint32_t g2 = 0;
                for (;;) {
                    u32x4 f = ldflags(fl, loc);
                    uint32_t mn = f.x < f.y ? f.x : f.y;
                    const uint32_t mn2 = f.z < f.w ? f.z : f.w;
                    if (mn2 < mn) mn = mn2;
                    if (mn >= (uint32_t)t || ++g2 >= (1u << 16)) break;
                }
                const char* src = (const char*)hbuf + (size_t)((t & 1) * 16 + cl) * 8192
                                + wu * 2048 + lane * 16;
                const bf16x8 r0 = ld16(src, loc);
                const bf16x8 r1 = ld16(src + 1024, loc);
                asm volatile("s_waitcnt vmcnt(0)" ::: "memory");
                __builtin_amdgcn_sched_barrier(0);
                AfrV[swz(512 + wu * 128 + lane)]      = r0;
                AfrV[swz(512 + wu * 128 + lane + 64)] = r1;
            }
        }
        __syncthreads();   // B2: A tile ready

        // ---- ks==0: issue x(t+1) prefetch (hides under MFMA+gates) ----
        if (ks == 0 && t + 1 < Tn) {
            const float* xs = xbase + (size_t)(t + 1) * In;
#pragma unroll
            for (int cc = 0; cc < 2; ++cc) {
                const int o8 = l15 + cc * 16;
                xp[cc * 2]     = *(const float4*)(xs + o8 * 8);
                xp[cc * 2 + 1] = *(const float4*)(xs + o8 * 8 + 4);
            }
        }

        // ---- MFMA: 8 frags x 4 gates on resident weights ----
        f32x4 acc[4] = {};
        bf16x8 af[8];
#pragma unroll
        for (int i = 0; i < 8; ++i)
            af[i] = AfrV[swz((ks * 8 + i) * 64 + lane)];
#pragma unroll
        for (int i = 0; i < 8; ++i)
#pragma unroll
            for (int g = 0; g < 4; ++g)
                acc[g] = __builtin_amdgcn_mfma_f32_16x16x32_bf16(af[i], wf[g][i], acc[g], 0, 0, 0);

        if (ks == 1) {
#pragma unroll
            for (int g = 0; g < 4; ++g) Red[wu][g][lane] = acc[g];
        }
        __syncthreads();   // B3: partials ready; A fully consumed (af in regs)

        // ---- ks==0: reduce + gates + in-wave transpose export ----
        if (ks == 0) {
#pragma unroll
            for (int g = 0; g < 4; ++g) acc[g] += Red[wu][g][lane];
            __hip_bfloat16* tp = (__hip_bfloat16*)&Tp[wu][0];
#pragma unroll
            for (int r = 0; r < 4; ++r) {
                const float pi = acc[0][r] + bg[0];
                const float pj = acc[1][r] + bg[1];
                const float pf = acc[2][r] + bg[2];
                const float po = acc[3][r] + bg[3];
                const float ai = sigmoidf_(pi);
                const float aj = tanhf_(pj);
                const float afv = sigmoidf_(pf);
                const float ao = sigmoidf_(po);
                const float cn = ai * aj + c4[r] * afv;
                c4[r] = cn;
                const float hn = ao * tanhf_(cn);
                if (t < Tn - 1) {
                    const int cp = (lk * 4 + r) * 2 + (l15 >> 3);   // (batch row, unit octet)
                    tp[swz16(cp) * 8 + (l15 & 7)] = __float2bfloat16(hn);
                } else {
                    out[(size_t)(cl * 16 + lk * 4 + r) * Hn + j * 64 + wu * 16 + l15] = hn;
                }
            }
            if (t < Tn - 1) {
                if (lane < 32) {
                    const bf16x8 val = Tp[wu][swz16(lane)];   // logical (row=lane>>1, oct=lane&1)
                    char* dst = (char*)hbuf + (size_t)(((t + 1) & 1) * 16 + cl) * 8192
                              + j * 2048 + (wu >> 1) * 1024
                              + ((lane >> 1) + 16 * ((wu & 1) * 2 + (lane & 1))) * 16;
                    st16(dst, val, loc);
                }
                asm volatile("s_waitcnt vmcnt(0)" ::: "memory");   // data at coherence point
                if (lane == 0)
                    stdw((char*)flags + (cl * 4 + j) * 16 + wu * 4, (uint32_t)(t + 1), loc);
            }
        }
        __syncthreads();   // B4: Tp writes visible before next-iter own-member import
    }
}

// ====================== FALLBACK (R3, passing) ==============================
__global__ void pack_w(const float* __restrict__ W, __hip_bfloat16* __restrict__ Wp) {
    int idx = blockIdx.x * 256 + threadIdx.x;
    int e = idx & 7, l = (idx >> 3) & 63, kb = (idx >> 9) & 15, nt = idx >> 13;
    int n = nt * 16 + (l & 15);
    int k = kb * 32 + (l >> 4) * 8 + e;
    Wp[idx] = __float2bfloat16(W[n * Kn + k]);
}

__global__ __launch_bounds__(1024, 4) void lstm_fused(
    const float* __restrict__ X, const float* __restrict__ bias,
    const __hip_bfloat16* __restrict__ Wp, float* __restrict__ out)
{
    constexpr int LDA = Kn + 8;
    __shared__ __hip_bfloat16 A[16][LDA];
    const int tid = threadIdx.x, wv = tid >> 6, lane = tid & 63;
    const int l15 = lane & 15, lk = lane >> 4, b0 = blockIdx.x * 16;
    const __hip_bfloat16* wp[4];
#pragma unroll
    for (int g = 0; g < 4; ++g) wp[g] = Wp + (size_t)(g * 16 + wv) * (16 * 512) + lane * 8;
    float bslot[4];
#pragma unroll
    for (int g = 0; g < 4; ++g) bslot[g] = bias[g * 256 + wv * 16 + l15];
    float c[4], h[4];
#pragma unroll
    for (int r = 0; r < 4; ++r) { c[r] = 0.f; h[r] = 0.f; }
    const float* xptr = X + ((size_t)(b0 + wv) * Tn) * In + lane * 4;
#pragma unroll 1
    for (int t = 0; t < Tn; ++t) {
        __syncthreads();
        {
            const float4 v = *(const float4*)(xptr + (size_t)t * In);
            __hip_bfloat16 tmp[4];
            tmp[0] = __float2bfloat16(v.x); tmp[1] = __float2bfloat16(v.y);
            tmp[2] = __float2bfloat16(v.z); tmp[3] = __float2bfloat16(v.w);
            *(ushort4*)&A[wv][lane * 4] = *(const ushort4*)tmp;
        }
#pragma unroll
        for (int r = 0; r < 4; ++r)
            A[lk * 4 + r][In + wv * 16 + l15] = __float2bfloat16(h[r]);
        __syncthreads();
        f32x4 acc[4];
#pragma unroll
        for (int g = 0; g < 4; ++g) acc[g] = f32x4{bslot[g], bslot[g], bslot[g], bslot[g]};
        bf16x8 wbuf[2][4];
#pragma unroll
        for (int g = 0; g < 4; ++g) wbuf[0][g] = *(const bf16x8*)(wp[g]);
#pragma unroll
        for (int kb = 0; kb < 16; ++kb) {
            const int cur = kb & 1;
            if (kb < 15) {
#pragma unroll
                for (int g = 0; g < 4; ++g)
                    wbuf[cur ^ 1][g] = *(const bf16x8*)(wp[g] + (kb + 1) * 512);
            }
            const bf16x8 a = *(const bf16x8*)&A[l15][kb * 32 + lk * 8];
#pragma unroll
            for (int g = 0; g < 4; ++g)
                acc[g] = __builtin_amdgcn_mfma_f32_16x16x32_bf16(a, wbuf[cur][g], acc[g], 0, 0, 0);
        }
#pragma unroll
        for (int r = 0; r < 4; ++r) {
            const float ai = sigmoidf_(acc[0][r]);
            const float aj = tanhf_(acc[1][r]);
            const float af = sigmoidf_(acc[2][r]);
            const float ao = sigmoidf_(acc[3][r]);
            const float cn = ai * aj + c[r] * af;
            c[r] = cn;
            h[r] = ao * tanhf_(cn);
            if (t == Tn - 1)
                out[(size_t)(b0 + lk * 4 + r) * Hn + wv * 16 + l15] = h[r];
        }
    }
}

} // namespace

extern "C" void kernel_launch(void* const* d_in, const int* in_sizes, int n_in,
                              void* d_out, int out_size, void* d_ws, size_t ws_size,
                              hipStream_t stream) {
    const float* X    = (const float*)d_in[0];   // [256][512][256] f32
    const float* W    = (const float*)d_in[1];   // [1024][512] f32
    const float* bias = (const float*)d_in[2];   // [1024] f32

    if (ws_size >= (size_t)0x142000) {
        // Wpf @0 (1MB), hbuf @0x100000 (256KB),
        // sync block @0x140000: flags 1KB, tokens 1KB, votes 256B
        __hip_bfloat16* Wpf    = (__hip_bfloat16*)d_ws;
        __hip_bfloat16* hbuf   = (__hip_bfloat16*)((char*)d_ws + 0x100000);
        uint32_t*       sync   = (uint32_t*)((char*)d_ws + 0x140000);
        uint32_t*       flags  = sync;
        uint32_t*       tokens = sync + 256;
        uint32_t*       votes  = sync + 512;
        pack_w_frag<<<dim3(256), dim3(256), 0, stream>>>(W, Wpf, sync);
        lstm_cluster<<<dim3(64), dim3(512), 0, stream>>>(X, bias, Wpf, hbuf,
                                                         flags, tokens, votes, (float*)d_out);
    } else {
        __hip_bfloat16* Wp = (__hip_bfloat16*)d_ws;
        pack_w<<<dim3(2048), dim3(256), 0, stream>>>(W, Wp);
        lstm_fused<<<dim3(16), dim3(1024), 0, stream>>>(X, bias, Wp, (float*)d_out);
    }
}

// Round 9
// 1724.642 us; speedup vs baseline: 3.2975x; 3.2975x over previous
//
#include <hip/hip_runtime.h>
#include <hip/hip_bf16.h>
#include <stdint.h>

namespace {

constexpr int Tn = 512, In = 256, Hn = 256, Kn = 512;

typedef __attribute__((ext_vector_type(8))) short bf16x8;
typedef __attribute__((ext_vector_type(4))) float f32x4;
typedef __attribute__((ext_vector_type(4))) unsigned int u32x4;

__device__ __forceinline__ float sigmoidf_(float x) { return 1.f / (1.f + __expf(-x)); }
__device__ __forceinline__ float tanhf_(float x)    { return 2.f / (1.f + __expf(-2.f * x)) - 1.f; }

// A-tile chunk swizzle (R5-validated): kills 16-way ds conflicts in staging
__device__ __forceinline__ int swz(int c) { return c ^ ((c >> 4) & 15); }
// transpose-patch chunk swizzle (involution on [0,32))
__device__ __forceinline__ int swz16(int c) { return c ^ (((c >> 3) & 3) << 1); }

// sc1 = agent/LLC-coherent ops. The ONLY prompt cross-WG channel on gfx950
// (R5 proved 3.3us/step; R8 proved sc0 cross-L2 is eviction-delayed ~us-scale).
__device__ __forceinline__ void st16_llc(void* p, bf16x8 v) {
    asm volatile("global_store_dwordx4 %0, %1, off sc1" :: "v"(p), "v"(v) : "memory");
}
__device__ __forceinline__ bf16x8 ld16_llc(const void* p) {
    bf16x8 r;
    asm volatile("global_load_dwordx4 %0, %1, off sc1" : "=v"(r) : "v"(p) : "memory");
    return r;
}
__device__ __forceinline__ u32x4 ldflags_llc(const void* p) {
    u32x4 r;
    asm volatile("global_load_dwordx4 %0, %1, off sc1\n\ts_waitcnt vmcnt(0)"
                 : "=v"(r) : "v"(p) : "memory");
    return r;
}
__device__ __forceinline__ void stflag_llc(void* p, uint32_t v) {
    asm volatile("global_store_dword %0, %1, off sc1" :: "v"(p), "v"(v) : "memory");
}

// ============================ FAST PATH =====================================
// 64 WGs: wg = cl + 16*j. Cluster cl owns batch [16cl,+16); member j owns units [64j,+64).
// 8 waves: w8 = ks*4 + wu. wu -> 16-unit sub-slice; ks -> K-half. Weights VGPR-resident.
// Pipeline: ks=0 waves run the x-GEMM (kb 0..7, LDS x dbuf staged 1 step ahead)
// BEFORE B2, overlapping ks=1 waves' h(t-1) poll+import. Post-B2: ks=1 h-GEMM.
// Post-B3: gates on ks=0 (acc_x + Red), export via same-wave Tp transpose; own
// member's h written straight into the LDS h-region (no global hop, no B4).

__global__ void pack_w_frag(const float* __restrict__ W, __hip_bfloat16* __restrict__ Wpf,
                            uint32_t* __restrict__ flags) {
    int idx  = blockIdx.x * 256 + threadIdx.x;
    int lane = idx & 63;
    int kb   = (idx >> 6) & 15;
    int nt2  = idx >> 10;
    int g = nt2 & 3, wu = (nt2 >> 2) & 3, jj = nt2 >> 4;
    int row = g * 256 + jj * 64 + wu * 16 + (lane & 15);
    int k0  = kb * 32 + (lane >> 4) * 8;
    const float* src = W + (size_t)row * Kn + k0;
    union { __hip_bfloat16 h[8]; bf16x8 v; } u;
#pragma unroll
    for (int e = 0; e < 8; ++e) u.h[e] = __float2bfloat16(src[e]);
    *(bf16x8*)(Wpf + (size_t)idx * 8) = u.v;
    // zero the 64x4 member flags EVERY launch (graph replays reuse ws; the
    // monotonic flags must restart at 0). Kernel-boundary release/acquire
    // makes these visible to lstm_cluster.
    if (blockIdx.x == 0 && threadIdx.x < 256)
        flags[threadIdx.x] = 0u;
}

__global__ __launch_bounds__(512, 2) void lstm_cluster(
    const float* __restrict__ X, const float* __restrict__ bias,
    const __hip_bfloat16* __restrict__ Wpf, __hip_bfloat16* __restrict__ hbuf,
    uint32_t* __restrict__ flags, float* __restrict__ out)
{
    __shared__ bf16x8 AfrX[2][512];    // 16 KB double-buffered x frags (kb 0..7)
    __shared__ bf16x8 AfrH[512];       // 8 KB h frags (kb 8..15)
    __shared__ f32x4 Red[4][4][64];    // 16 KB h-GEMM partials
    __shared__ bf16x8 Tp[4][32];       // 2 KB per-gate-wave transpose patches

    const int tid = threadIdx.x, lane = tid & 63, w8 = tid >> 6;
    const int wu = w8 & 3, ks = w8 >> 2;
    const int l15 = lane & 15, lk = lane >> 4;
    const int wg = blockIdx.x, cl = wg & 15, j = wg >> 4;

    // ---- resident weights: 32 frags / lane (ks picks the K-half) ----
    bf16x8 wf[4][8];
#pragma unroll
    for (int g = 0; g < 4; ++g)
#pragma unroll
        for (int i = 0; i < 8; ++i) {
            const int nt2 = (j * 4 + wu) * 4 + g, kb = ks * 8 + i;
            wf[g][i] = *(const bf16x8*)(Wpf + ((size_t)(nt2 * 16 + kb) * 64 + lane) * 8);
        }
    float bg[4];
#pragma unroll
    for (int g = 0; g < 4; ++g) bg[g] = bias[g * 256 + j * 64 + wu * 16 + l15];

    float c4[4] = {0.f, 0.f, 0.f, 0.f};

    // zero h region (h(-1) = 0)
    {
        const bf16x8 z = {};
        AfrH[tid] = z;
    }

    // ---- prologue: stage x(0) into buf0; prefetch xp = x(1) ----
    const int b = wu * 4 + lk;   // batch row within cluster (ks==0 staging role)
    const float* xbase = X + (size_t)(cl * 16 + b) * Tn * In;
    float4 xp[4];
    if (ks == 0) {
#pragma unroll
        for (int cc = 0; cc < 2; ++cc) {
            const int o8 = l15 + cc * 16;
            const float4 v0 = *(const float4*)(xbase + o8 * 8);
            const float4 v1 = *(const float4*)(xbase + o8 * 8 + 4);
            union { __hip_bfloat16 h[8]; bf16x8 v; } u;
            u.h[0] = __float2bfloat16(v0.x); u.h[1] = __float2bfloat16(v0.y);
            u.h[2] = __float2bfloat16(v0.z); u.h[3] = __float2bfloat16(v0.w);
            u.h[4] = __float2bfloat16(v1.x); u.h[5] = __float2bfloat16(v1.y);
            u.h[6] = __float2bfloat16(v1.z); u.h[7] = __float2bfloat16(v1.w);
            AfrX[0][swz(b + 16 * o8)] = u.v;
        }
#pragma unroll
        for (int cc = 0; cc < 2; ++cc) {
            const int o8 = l15 + cc * 16;
            xp[cc * 2]     = *(const float4*)(xbase + In + o8 * 8);
            xp[cc * 2 + 1] = *(const float4*)(xbase + In + o8 * 8 + 4);
        }
    }
    __syncthreads();

#pragma unroll 1
    for (int t = 0; t < Tn; ++t) {
        f32x4 acc[4] = {};

        if (ks == 0) {
            // ---- x-GEMM(t) from LDS dbuf: runs DURING mates' h import ----
            bf16x8 af[8];
#pragma unroll
            for (int i = 0; i < 8; ++i)
                af[i] = AfrX[t & 1][swz(i * 64 + lane)];
#pragma unroll
            for (int i = 0; i < 8; ++i)
#pragma unroll
                for (int g = 0; g < 4; ++g)
                    acc[g] = __builtin_amdgcn_mfma_f32_16x16x32_bf16(af[i], wf[g][i], acc[g], 0, 0, 0);
            // ---- stage x(t+1) from prefetch regs ----
            if (t + 1 < Tn) {
#pragma unroll
                for (int cc = 0; cc < 2; ++cc) {
                    const int o8 = l15 + cc * 16;
                    union { __hip_bfloat16 h[8]; bf16x8 v; } u;
                    u.h[0] = __float2bfloat16(xp[cc * 2].x); u.h[1] = __float2bfloat16(xp[cc * 2].y);
                    u.h[2] = __float2bfloat16(xp[cc * 2].z); u.h[3] = __float2bfloat16(xp[cc * 2].w);
                    u.h[4] = __float2bfloat16(xp[cc * 2 + 1].x); u.h[5] = __float2bfloat16(xp[cc * 2 + 1].y);
                    u.h[6] = __float2bfloat16(xp[cc * 2 + 1].z); u.h[7] = __float2bfloat16(xp[cc * 2 + 1].w);
                    AfrX[(t + 1) & 1][swz(b + 16 * o8)] = u.v;
                }
            }
        } else if (t > 0 && wu != j) {
            // ---- import h(t-1) of mate wu (own member j arrives via LDS) ----
            const char* fl = (const char*)flags + (cl * 4 + wu) * 16;
            uint32_t g2 = 0;
            for (;;) {
                u32x4 f = ldflags_llc(fl);
                uint32_t mn = f.x < f.y ? f.x : f.y;
                const uint32_t mn2 = f.z < f.w ? f.z : f.w;
                if (mn2 < mn) mn = mn2;
                if (mn >= (uint32_t)t || ++g2 >= (1u << 12)) break;
            }
            const char* src = (const char*)hbuf + (size_t)((t & 1) * 16 + cl) * 8192
                            + wu * 2048 + lane * 16;
            const bf16x8 r0 = ld16_llc(src);
            const bf16x8 r1 = ld16_llc(src + 1024);
            asm volatile("s_waitcnt vmcnt(0)" ::: "memory");
            __builtin_amdgcn_sched_barrier(0);
            AfrH[swz(wu * 128 + lane)]      = r0;
            AfrH[swz(wu * 128 + lane + 64)] = r1;
        }
        __syncthreads();   // B2: h(t-1) fully in AfrH; x(t+1) staged

        if (ks == 0) {
            // issue x(t+2) prefetch (hides under h-GEMM + gates)
            if (t + 2 < Tn) {
                const float* xs = xbase + (size_t)(t + 2) * In;
#pragma unroll
                for (int cc = 0; cc < 2; ++cc) {
                    const int o8 = l15 + cc * 16;
                    xp[cc * 2]     = *(const float4*)(xs + o8 * 8);
                    xp[cc * 2 + 1] = *(const float4*)(xs + o8 * 8 + 4);
                }
            }
        } else {
            // ---- h-GEMM(t): kb 8..15 on h(t-1) ----
            bf16x8 af[8];
#pragma unroll
            for (int i = 0; i < 8; ++i)
                af[i] = AfrH[swz(i * 64 + lane)];
#pragma unroll
            for (int i = 0; i < 8; ++i)
#pragma unroll
                for (int g = 0; g < 4; ++g)
                    acc[g] = __builtin_amdgcn_mfma_f32_16x16x32_bf16(af[i], wf[g][i], acc[g], 0, 0, 0);
#pragma unroll
            for (int g = 0; g < 4; ++g) Red[wu][g][lane] = acc[g];
        }
        __syncthreads();   // B3: Red ready; all AfrH reads of h(t-1) done

        if (ks == 0) {
            // ---- reduce + gates ----
#pragma unroll
            for (int g = 0; g < 4; ++g) acc[g] += Red[wu][g][lane];
            __hip_bfloat16* tp = (__hip_bfloat16*)&Tp[wu][0];
#pragma unroll
            for (int r = 0; r < 4; ++r) {
                const float pi = acc[0][r] + bg[0];
                const float pj = acc[1][r] + bg[1];
                const float pf = acc[2][r] + bg[2];
                const float po = acc[3][r] + bg[3];
                const float ai = sigmoidf_(pi);
                const float aj = tanhf_(pj);
                const float afv = sigmoidf_(pf);
                const float ao = sigmoidf_(po);
                const float cn = ai * aj + c4[r] * afv;
                c4[r] = cn;
                const float hn = ao * tanhf_(cn);
                if (t < Tn - 1) {
                    const int cp = (lk * 4 + r) * 2 + (l15 >> 3);   // (batch row, unit octet)
                    tp[swz16(cp) * 8 + (l15 & 7)] = __float2bfloat16(hn);
                } else {
                    out[(size_t)(cl * 16 + lk * 4 + r) * Hn + j * 64 + wu * 16 + l15] = hn;
                }
            }
            if (t < Tn - 1) {
                // same-wave Tp transpose -> (a) own-h direct to LDS h-region,
                // (b) sc1 export to the 3 mates, (c) flag
                if (lane < 32) {
                    const bf16x8 val = Tp[wu][swz16(lane)];   // (row=lane>>1, oct=lane&1)
                    const int clocal = (wu >> 1) * 64 + (lane >> 1)
                                     + 16 * ((wu & 1) * 2 + (lane & 1));
                    AfrH[swz(j * 128 + clocal)] = val;        // own member: no global hop
                    char* dst = (char*)hbuf + (size_t)(((t + 1) & 1) * 16 + cl) * 8192
                              + j * 2048 + clocal * 16;
                    st16_llc(dst, val);
                }
                asm volatile("s_waitcnt vmcnt(0)" ::: "memory");   // data at LLC before flag
                if (lane == 0)
                    stflag_llc((char*)flags + (cl * 4 + j) * 16 + wu * 4, (uint32_t)(t + 1));
            }
        }
        // no B4: Tp is same-wave only; own-h AfrH writes (post-B3) are ordered
        // against next step's h-GEMM reads by B2(t+1).
    }
}

// ====================== FALLBACK (R3, passing) ==============================
__global__ void pack_w(const float* __restrict__ W, __hip_bfloat16* __restrict__ Wp) {
    int idx = blockIdx.x * 256 + threadIdx.x;
    int e = idx & 7, l = (idx >> 3) & 63, kb = (idx >> 9) & 15, nt = idx >> 13;
    int n = nt * 16 + (l & 15);
    int k = kb * 32 + (l >> 4) * 8 + e;
    Wp[idx] = __float2bfloat16(W[n * Kn + k]);
}

__global__ __launch_bounds__(1024, 4) void lstm_fused(
    const float* __restrict__ X, const float* __restrict__ bias,
    const __hip_bfloat16* __restrict__ Wp, float* __restrict__ out)
{
    constexpr int LDA = Kn + 8;
    __shared__ __hip_bfloat16 A[16][LDA];
    const int tid = threadIdx.x, wv = tid >> 6, lane = tid & 63;
    const int l15 = lane & 15, lk = lane >> 4, b0 = blockIdx.x * 16;
    const __hip_bfloat16* wp[4];
#pragma unroll
    for (int g = 0; g < 4; ++g) wp[g] = Wp + (size_t)(g * 16 + wv) * (16 * 512) + lane * 8;
    float bslot[4];
#pragma unroll
    for (int g = 0; g < 4; ++g) bslot[g] = bias[g * 256 + wv * 16 + l15];
    float c[4], h[4];
#pragma unroll
    for (int r = 0; r < 4; ++r) { c[r] = 0.f; h[r] = 0.f; }
    const float* xptr = X + ((size_t)(b0 + wv) * Tn) * In + lane * 4;
#pragma unroll 1
    for (int t = 0; t < Tn; ++t) {
        __syncthreads();
        {
            const float4 v = *(const float4*)(xptr + (size_t)t * In);
            __hip_bfloat16 tmp[4];
            tmp[0] = __float2bfloat16(v.x); tmp[1] = __float2bfloat16(v.y);
            tmp[2] = __float2bfloat16(v.z); tmp[3] = __float2bfloat16(v.w);
            *(ushort4*)&A[wv][lane * 4] = *(const ushort4*)tmp;
        }
#pragma unroll
        for (int r = 0; r < 4; ++r)
            A[lk * 4 + r][In + wv * 16 + l15] = __float2bfloat16(h[r]);
        __syncthreads();
        f32x4 acc[4];
#pragma unroll
        for (int g = 0; g < 4; ++g) acc[g] = f32x4{bslot[g], bslot[g], bslot[g], bslot[g]};
        bf16x8 wbuf[2][4];
#pragma unroll
        for (int g = 0; g < 4; ++g) wbuf[0][g] = *(const bf16x8*)(wp[g]);
#pragma unroll
        for (int kb = 0; kb < 16; ++kb) {
            const int cur = kb & 1;
            if (kb < 15) {
#pragma unroll
                for (int g = 0; g < 4; ++g)
                    wbuf[cur ^ 1][g] = *(const bf16x8*)(wp[g] + (kb + 1) * 512);
            }
            const bf16x8 a = *(const bf16x8*)&A[l15][kb * 32 + lk * 8];
#pragma unroll
            for (int g = 0; g < 4; ++g)
                acc[g] = __builtin_amdgcn_mfma_f32_16x16x32_bf16(a, wbuf[cur][g], acc[g], 0, 0, 0);
        }
#pragma unroll
        for (int r = 0; r < 4; ++r) {
            const float ai = sigmoidf_(acc[0][r]);
            const float aj = tanhf_(acc[1][r]);
            const float af = sigmoidf_(acc[2][r]);
            const float ao = sigmoidf_(acc[3][r]);
            const float cn = ai * aj + c[r] * af;
            c[r] = cn;
            h[r] = ao * tanhf_(cn);
            if (t == Tn - 1)
                out[(size_t)(b0 + lk * 4 + r) * Hn + wv * 16 + l15] = h[r];
        }
    }
}

} // namespace

extern "C" void kernel_launch(void* const* d_in, const int* in_sizes, int n_in,
                              void* d_out, int out_size, void* d_ws, size_t ws_size,
                              hipStream_t stream) {
    const float* X    = (const float*)d_in[0];   // [256][512][256] f32
    const float* W    = (const float*)d_in[1];   // [1024][512] f32
    const float* bias = (const float*)d_in[2];   // [1024] f32

    if (ws_size >= (size_t)0x142000) {
        // Wpf @0 (1MB), hbuf @0x100000 (256KB), flags @0x140000 (1KB)
        __hip_bfloat16* Wpf   = (__hip_bfloat16*)d_ws;
        __hip_bfloat16* hbuf  = (__hip_bfloat16*)((char*)d_ws + 0x100000);
        uint32_t*       flags = (uint32_t*)((char*)d_ws + 0x140000);
        pack_w_frag<<<dim3(256), dim3(256), 0, stream>>>(W, Wpf, flags);
        lstm_cluster<<<dim3(64), dim3(512), 0, stream>>>(X, bias, Wpf, hbuf, flags,
                                                         (float*)d_out);
    } else {
        __hip_bfloat16* Wp = (__hip_bfloat16*)d_ws;
        pack_w<<<dim3(2048), dim3(256), 0, stream>>>(W, Wp);
        lstm_fused<<<dim3(16), dim3(1024), 0, stream>>>(X, bias, Wp, (float*)d_out);
    }
}

// Round 10
// 1513.986 us; speedup vs baseline: 3.7563x; 1.1391x over previous
//
#include <hip/hip_runtime.h>
#include <hip/hip_bf16.h>
#include <stdint.h>

namespace {

constexpr int Tn = 512, In = 256, Hn = 256, Kn = 512;

typedef __attribute__((ext_vector_type(8))) short bf16x8;
typedef __attribute__((ext_vector_type(4))) float f32x4;
typedef __attribute__((ext_vector_type(4))) unsigned int u32x4;

__device__ __forceinline__ float sigmoidf_(float x) { return 1.f / (1.f + __expf(-x)); }
__device__ __forceinline__ float tanhf_(float x)    { return 2.f / (1.f + __expf(-2.f * x)) - 1.f; }

// A-tile chunk swizzle (R5-validated): kills 16-way ds conflicts in staging
__device__ __forceinline__ int swz(int c) { return c ^ ((c >> 4) & 15); }
// transpose-patch chunk swizzle (R9 mid-tier only)
__device__ __forceinline__ int swz16(int c) { return c ^ (((c >> 3) & 3) << 1); }

// sc1 = agent/LLC-coherent ops (R5-proven prompt cross-WG channel)
__device__ __forceinline__ void st16_llc(void* p, bf16x8 v) {
    asm volatile("global_store_dwordx4 %0, %1, off sc1" :: "v"(p), "v"(v) : "memory");
}
__device__ __forceinline__ bf16x8 ld16_llc(const void* p) {
    bf16x8 r;
    asm volatile("global_load_dwordx4 %0, %1, off sc1" : "=v"(r) : "v"(p) : "memory");
    return r;
}
__device__ __forceinline__ u32x4 ld16u_llc(const void* p) {
    u32x4 r;
    asm volatile("global_load_dwordx4 %0, %1, off sc1" : "=v"(r) : "v"(p) : "memory");
    return r;
}
__device__ __forceinline__ u32x4 ldflags_llc(const void* p) {
    u32x4 r;
    asm volatile("global_load_dwordx4 %0, %1, off sc1\n\ts_waitcnt vmcnt(0)"
                 : "=v"(r) : "v"(p) : "memory");
    return r;
}
__device__ __forceinline__ void stdw_llc(void* p, uint32_t v) {
    asm volatile("global_store_dword %0, %1, off sc1" :: "v"(p), "v"(v) : "memory");
}

// tag check: 8 dwords, hi-u16 must all equal want (wt = want<<16)
__device__ __forceinline__ bool tags8(u32x4 a, u32x4 b, uint32_t wt) {
    uint32_t d = (a.x ^ wt) | (a.y ^ wt) | (a.z ^ wt) | (a.w ^ wt)
               | (b.x ^ wt) | (b.y ^ wt) | (b.z ^ wt) | (b.w ^ wt);
    return (d & 0xFFFF0000u) == 0u;
}
// pack 8 payload-lo16s -> bf16x8
__device__ __forceinline__ bf16x8 pack8(u32x4 a, u32x4 b) {
    union { uint32_t u[4]; bf16x8 v; } r;
    r.u[0] = (a.x & 0xFFFFu) | (a.y << 16);
    r.u[1] = (a.z & 0xFFFFu) | (a.w << 16);
    r.u[2] = (b.x & 0xFFFFu) | (b.y << 16);
    r.u[3] = (b.z & 0xFFFFu) | (b.w << 16);
    return r.v;
}

// ===================== TIER 1: tag-in-data exchange =========================
// 64 WGs: wg = cl + 16*j. Cluster cl owns batch [16cl,+16); member j owns units [64j,+64).
// 8 waves: w8 = ks*4 + wu. ks=0: x-GEMM+staging+gates. ks=1: mate-h import + h-GEMM.
// hbuf member stream (4KB x 2 parity): dword i = m*64 + lu  = {lo: bf16 h, hi: u16 tag}.
// Tag t+1 written at end of step t; consumer at step t polls for tag == t. Dword
// single-copy atomicity makes per-dword tag+payload indivisible (no torn reads).

__global__ void pack_w_tag(const float* __restrict__ W, __hip_bfloat16* __restrict__ Wpf,
                           unsigned long long* __restrict__ hz) {
    int idx  = blockIdx.x * 256 + threadIdx.x;   // 65536 total
    int lane = idx & 63;
    int kb   = (idx >> 6) & 15;
    int nt2  = idx >> 10;
    int g = nt2 & 3, wu = (nt2 >> 2) & 3, jj = nt2 >> 4;
    int row = g * 256 + jj * 64 + wu * 16 + (lane & 15);
    int k0  = kb * 32 + (lane >> 4) * 8;
    const float* src = W + (size_t)row * Kn + k0;
    union { __hip_bfloat16 h[8]; bf16x8 v; } u;
#pragma unroll
    for (int e = 0; e < 8; ++e) u.h[e] = __float2bfloat16(src[e]);
    *(bf16x8*)(Wpf + (size_t)idx * 8) = u.v;
    // zero hbuf (512KB) EVERY launch: stale tags from a previous replay could
    // alias wanted tags (tag space reused). 65536 threads x 8B.
    hz[idx] = 0ULL;
}

__global__ __launch_bounds__(512, 2) void lstm_tag(
    const float* __restrict__ X, const float* __restrict__ bias,
    const __hip_bfloat16* __restrict__ Wpf, char* __restrict__ hbuf,
    float* __restrict__ out)
{
    __shared__ bf16x8 AfrX[2][512];    // 16 KB double-buffered x frags (kb 0..7)
    __shared__ bf16x8 AfrH[512];       // 8 KB h frags (kb 8..15)
    __shared__ f32x4 Red[4][4][64];    // 16 KB h-GEMM partials

    const int tid = threadIdx.x, lane = tid & 63, w8 = tid >> 6;
    const int wu = w8 & 3, ks = w8 >> 2;
    const int l15 = lane & 15, lk = lane >> 4;
    const int wg = blockIdx.x, cl = wg & 15, j = wg >> 4;

    // ---- resident weights: 32 frags / lane (ks picks the K-half) ----
    bf16x8 wf[4][8];
#pragma unroll
    for (int g = 0; g < 4; ++g)
#pragma unroll
        for (int i = 0; i < 8; ++i) {
            const int nt2 = (j * 4 + wu) * 4 + g, kb = ks * 8 + i;
            wf[g][i] = *(const bf16x8*)(Wpf + ((size_t)(nt2 * 16 + kb) * 64 + lane) * 8);
        }
    float bg[4];
#pragma unroll
    for (int g = 0; g < 4; ++g) bg[g] = bias[g * 256 + j * 64 + wu * 16 + l15];

    float c4[4] = {0.f, 0.f, 0.f, 0.f};

    // zero h region (h(-1) = 0)
    {
        const bf16x8 z = {};
        AfrH[tid] = z;
    }

    // ---- prologue: stage x(0); prefetch x(1) ----
    const int b = wu * 4 + lk;
    const float* xbase = X + (size_t)(cl * 16 + b) * Tn * In;
    float4 xp[4];
    if (ks == 0) {
#pragma unroll
        for (int cc = 0; cc < 2; ++cc) {
            const int o8 = l15 + cc * 16;
            const float4 v0 = *(const float4*)(xbase + o8 * 8);
            const float4 v1 = *(const float4*)(xbase + o8 * 8 + 4);
            union { __hip_bfloat16 h[8]; bf16x8 v; } u;
            u.h[0] = __float2bfloat16(v0.x); u.h[1] = __float2bfloat16(v0.y);
            u.h[2] = __float2bfloat16(v0.z); u.h[3] = __float2bfloat16(v0.w);
            u.h[4] = __float2bfloat16(v1.x); u.h[5] = __float2bfloat16(v1.y);
            u.h[6] = __float2bfloat16(v1.z); u.h[7] = __float2bfloat16(v1.w);
            AfrX[0][swz(b + 16 * o8)] = u.v;
        }
#pragma unroll
        for (int cc = 0; cc < 2; ++cc) {
            const int o8 = l15 + cc * 16;
            xp[cc * 2]     = *(const float4*)(xbase + In + o8 * 8);
            xp[cc * 2 + 1] = *(const float4*)(xbase + In + o8 * 8 + 4);
        }
    }
    __syncthreads();

#pragma unroll 1
    for (int t = 0; t < Tn; ++t) {
        f32x4 acc[4] = {};

        if (ks == 0) {
            // ---- x-GEMM(t): overlaps mates' h import ----
            bf16x8 af[8];
#pragma unroll
            for (int i = 0; i < 8; ++i)
                af[i] = AfrX[t & 1][swz(i * 64 + lane)];
#pragma unroll
            for (int i = 0; i < 8; ++i)
#pragma unroll
                for (int g = 0; g < 4; ++g)
                    acc[g] = __builtin_amdgcn_mfma_f32_16x16x32_bf16(af[i], wf[g][i], acc[g], 0, 0, 0);
            // ---- stage x(t+1) from prefetch regs ----
            if (t + 1 < Tn) {
#pragma unroll
                for (int cc = 0; cc < 2; ++cc) {
                    const int o8 = l15 + cc * 16;
                    union { __hip_bfloat16 h[8]; bf16x8 v; } u;
                    u.h[0] = __float2bfloat16(xp[cc * 2].x); u.h[1] = __float2bfloat16(xp[cc * 2].y);
                    u.h[2] = __float2bfloat16(xp[cc * 2].z); u.h[3] = __float2bfloat16(xp[cc * 2].w);
                    u.h[4] = __float2bfloat16(xp[cc * 2 + 1].x); u.h[5] = __float2bfloat16(xp[cc * 2 + 1].y);
                    u.h[6] = __float2bfloat16(xp[cc * 2 + 1].z); u.h[7] = __float2bfloat16(xp[cc * 2 + 1].w);
                    AfrX[(t + 1) & 1][swz(b + 16 * o8)] = u.v;
                }
            }
        } else if (t > 0 && wu != j) {
            // ---- import mate wu's h(t-1): poll the tagged data itself ----
            const char* ib = hbuf + (size_t)(((cl * 4 + wu) * 2 + (t & 1)) * 4096)
                           + (lane & 15) * 256 + (lane >> 4) * 32;
            const uint32_t wt = ((uint32_t)t) << 16;
            u32x4 A0 = {}, A1 = {}, B0 = {}, B1 = {};
            bool f0 = false, f1 = false;
            int g2 = 0;
            for (;;) {
                if (!f0) { A0 = ld16u_llc(ib);       A1 = ld16u_llc(ib + 16); }
                if (!f1) { B0 = ld16u_llc(ib + 128); B1 = ld16u_llc(ib + 144); }
                asm volatile("s_waitcnt vmcnt(0)" ::: "memory");
                f0 = f0 || tags8(A0, A1, wt);
                f1 = f1 || tags8(B0, B1, wt);
                if (__all(f0 && f1) || ++g2 >= 1024) break;
            }
            __builtin_amdgcn_sched_barrier(0);
            AfrH[swz(wu * 128 + lane)]      = pack8(A0, A1);
            AfrH[swz(wu * 128 + 64 + lane)] = pack8(B0, B1);
        }
        __syncthreads();   // B2: h(t-1) in AfrH; x(t+1) staged

        if (ks == 1) {
            // ---- h-GEMM(t): kb 8..15 on h(t-1) ----
            bf16x8 af[8];
#pragma unroll
            for (int i = 0; i < 8; ++i)
                af[i] = AfrH[swz(i * 64 + lane)];
#pragma unroll
            for (int i = 0; i < 8; ++i)
#pragma unroll
                for (int g = 0; g < 4; ++g)
                    acc[g] = __builtin_amdgcn_mfma_f32_16x16x32_bf16(af[i], wf[g][i], acc[g], 0, 0, 0);
#pragma unroll
            for (int g = 0; g < 4; ++g) Red[wu][g][lane] = acc[g];
        }
        __syncthreads();   // B3: Red ready

        if (ks == 0) {
            // ---- reduce + gates ----
#pragma unroll
            for (int g = 0; g < 4; ++g) acc[g] += Red[wu][g][lane];
            uint16_t hb[4];
#pragma unroll
            for (int r = 0; r < 4; ++r) {
                const float pi = acc[0][r] + bg[0];
                const float pj = acc[1][r] + bg[1];
                const float pf = acc[2][r] + bg[2];
                const float po = acc[3][r] + bg[3];
                const float ai = sigmoidf_(pi);
                const float aj = tanhf_(pj);
                const float afv = sigmoidf_(pf);
                const float ao = sigmoidf_(po);
                const float cn = ai * aj + c4[r] * afv;
                c4[r] = cn;
                const float hn = ao * tanhf_(cn);
                if (t < Tn - 1) {
                    union { __hip_bfloat16 bh; uint16_t u; } cv;
                    cv.bh = __float2bfloat16(hn);
                    hb[r] = cv.u;
                    // own member's h straight into AfrH (u16, 2-way bank alias = free)
                    const int c = j * 128 + (wu >> 1) * 64
                                + ((wu & 1) * 2 + (l15 >> 3)) * 16 + lk * 4 + r;
                    *(uint16_t*)((char*)AfrH + swz(c) * 16 + (l15 & 7) * 2) = hb[r];
                } else {
                    out[(size_t)(cl * 16 + lk * 4 + r) * Hn + j * 64 + wu * 16 + l15] = hn;
                }
            }
            if (t < Tn - 1) {
                // drain old exports (store-after-store same-address safety), then
                // fire-and-forget tagged dword stores. No ack, no flag.
                asm volatile("s_waitcnt vmcnt(0)" ::: "memory");
                char* eb = hbuf + (size_t)(((cl * 4 + j) * 2 + ((t + 1) & 1)) * 4096);
                const uint32_t tagw = ((uint32_t)(t + 1)) << 16;
#pragma unroll
                for (int r = 0; r < 4; ++r)
                    stdw_llc(eb + (((lk * 4 + r) * 64 + wu * 16 + l15) << 2),
                             (uint32_t)hb[r] | tagw);
                // issue x(t+2) prefetch (hides under next step's poll + h-GEMM)
                if (t + 2 < Tn) {
                    const float* xs = xbase + (size_t)(t + 2) * In;
#pragma unroll
                    for (int cc = 0; cc < 2; ++cc) {
                        const int o8 = l15 + cc * 16;
                        xp[cc * 2]     = *(const float4*)(xs + o8 * 8);
                        xp[cc * 2 + 1] = *(const float4*)(xs + o8 * 8 + 4);
                    }
                }
            }
        }
    }
}

// ===================== TIER 2: R9 flag protocol (proven 1724us) =============
__global__ void pack_w_frag(const float* __restrict__ W, __hip_bfloat16* __restrict__ Wpf,
                            uint32_t* __restrict__ flags) {
    int idx  = blockIdx.x * 256 + threadIdx.x;
    int lane = idx & 63;
    int kb   = (idx >> 6) & 15;
    int nt2  = idx >> 10;
    int g = nt2 & 3, wu = (nt2 >> 2) & 3, jj = nt2 >> 4;
    int row = g * 256 + jj * 64 + wu * 16 + (lane & 15);
    int k0  = kb * 32 + (lane >> 4) * 8;
    const float* src = W + (size_t)row * Kn + k0;
    union { __hip_bfloat16 h[8]; bf16x8 v; } u;
#pragma unroll
    for (int e = 0; e < 8; ++e) u.h[e] = __float2bfloat16(src[e]);
    *(bf16x8*)(Wpf + (size_t)idx * 8) = u.v;
    if (blockIdx.x == 0 && threadIdx.x < 256)
        flags[threadIdx.x] = 0u;
}

__global__ __launch_bounds__(512, 2) void lstm_cluster(
    const float* __restrict__ X, const float* __restrict__ bias,
    const __hip_bfloat16* __restrict__ Wpf, __hip_bfloat16* __restrict__ hbuf,
    uint32_t* __restrict__ flags, float* __restrict__ out)
{
    __shared__ bf16x8 AfrX[2][512];
    __shared__ bf16x8 AfrH[512];
    __shared__ f32x4 Red[4][4][64];
    __shared__ bf16x8 Tp[4][32];

    const int tid = threadIdx.x, lane = tid & 63, w8 = tid >> 6;
    const int wu = w8 & 3, ks = w8 >> 2;
    const int l15 = lane & 15, lk = lane >> 4;
    const int wg = blockIdx.x, cl = wg & 15, j = wg >> 4;

    bf16x8 wf[4][8];
#pragma unroll
    for (int g = 0; g < 4; ++g)
#pragma unroll
        for (int i = 0; i < 8; ++i) {
            const int nt2 = (j * 4 + wu) * 4 + g, kb = ks * 8 + i;
            wf[g][i] = *(const bf16x8*)(Wpf + ((size_t)(nt2 * 16 + kb) * 64 + lane) * 8);
        }
    float bg[4];
#pragma unroll
    for (int g = 0; g < 4; ++g) bg[g] = bias[g * 256 + j * 64 + wu * 16 + l15];
    float c4[4] = {0.f, 0.f, 0.f, 0.f};
    {
        const bf16x8 z = {};
        AfrH[tid] = z;
    }
    const int b = wu * 4 + lk;
    const float* xbase = X + (size_t)(cl * 16 + b) * Tn * In;
    float4 xp[4];
    if (ks == 0) {
#pragma unroll
        for (int cc = 0; cc < 2; ++cc) {
            const int o8 = l15 + cc * 16;
            const float4 v0 = *(const float4*)(xbase + o8 * 8);
            const float4 v1 = *(const float4*)(xbase + o8 * 8 + 4);
            union { __hip_bfloat16 h[8]; bf16x8 v; } u;
            u.h[0] = __float2bfloat16(v0.x); u.h[1] = __float2bfloat16(v0.y);
            u.h[2] = __float2bfloat16(v0.z); u.h[3] = __float2bfloat16(v0.w);
            u.h[4] = __float2bfloat16(v1.x); u.h[5] = __float2bfloat16(v1.y);
            u.h[6] = __float2bfloat16(v1.z); u.h[7] = __float2bfloat16(v1.w);
            AfrX[0][swz(b + 16 * o8)] = u.v;
        }
#pragma unroll
        for (int cc = 0; cc < 2; ++cc) {
            const int o8 = l15 + cc * 16;
            xp[cc * 2]     = *(const float4*)(xbase + In + o8 * 8);
            xp[cc * 2 + 1] = *(const float4*)(xbase + In + o8 * 8 + 4);
        }
    }
    __syncthreads();
#pragma unroll 1
    for (int t = 0; t < Tn; ++t) {
        f32x4 acc[4] = {};
        if (ks == 0) {
            bf16x8 af[8];
#pragma unroll
            for (int i = 0; i < 8; ++i)
                af[i] = AfrX[t & 1][swz(i * 64 + lane)];
#pragma unroll
            for (int i = 0; i < 8; ++i)
#pragma unroll
                for (int g = 0; g < 4; ++g)
                    acc[g] = __builtin_amdgcn_mfma_f32_16x16x32_bf16(af[i], wf[g][i], acc[g], 0, 0, 0);
            if (t + 1 < Tn) {
#pragma unroll
                for (int cc = 0; cc < 2; ++cc) {
                    const int o8 = l15 + cc * 16;
                    union { __hip_bfloat16 h[8]; bf16x8 v; } u;
                    u.h[0] = __float2bfloat16(xp[cc * 2].x); u.h[1] = __float2bfloat16(xp[cc * 2].y);
                    u.h[2] = __float2bfloat16(xp[cc * 2].z); u.h[3] = __float2bfloat16(xp[cc * 2].w);
                    u.h[4] = __float2bfloat16(xp[cc * 2 + 1].x); u.h[5] = __float2bfloat16(xp[cc * 2 + 1].y);
                    u.h[6] = __float2bfloat16(xp[cc * 2 + 1].z); u.h[7] = __float2bfloat16(xp[cc * 2 + 1].w);
                    AfrX[(t + 1) & 1][swz(b + 16 * o8)] = u.v;
                }
            }
        } else if (t > 0 && wu != j) {
            const char* fl = (const char*)flags + (cl * 4 + wu) * 16;
            uint32_t g2 = 0;
            for (;;) {
                u32x4 f = ldflags_llc(fl);
                uint32_t mn = f.x < f.y ? f.x : f.y;
                const uint32_t mn2 = f.z < f.w ? f.z : f.w;
                if (mn2 < mn) mn = mn2;
                if (mn >= (uint32_t)t || ++g2 >= (1u << 12)) break;
            }
            const char* src = (const char*)hbuf + (size_t)((t & 1) * 16 + cl) * 8192
                            + wu * 2048 + lane * 16;
            const bf16x8 r0 = ld16_llc(src);
            const bf16x8 r1 = ld16_llc(src + 1024);
            asm volatile("s_waitcnt vmcnt(0)" ::: "memory");
            __builtin_amdgcn_sched_barrier(0);
            AfrH[swz(wu * 128 + lane)]      = r0;
            AfrH[swz(wu * 128 + lane + 64)] = r1;
        }
        __syncthreads();
        if (ks == 0) {
            if (t + 2 < Tn) {
                const float* xs = xbase + (size_t)(t + 2) * In;
#pragma unroll
                for (int cc = 0; cc < 2; ++cc) {
                    const int o8 = l15 + cc * 16;
                    xp[cc * 2]     = *(const float4*)(xs + o8 * 8);
                    xp[cc * 2 + 1] = *(const float4*)(xs + o8 * 8 + 4);
                }
            }
        } else {
            bf16x8 af[8];
#pragma unroll
            for (int i = 0; i < 8; ++i)
                af[i] = AfrH[swz(i * 64 + lane)];
#pragma unroll
            for (int i = 0; i < 8; ++i)
#pragma unroll
                for (int g = 0; g < 4; ++g)
                    acc[g] = __builtin_amdgcn_mfma_f32_16x16x32_bf16(af[i], wf[g][i], acc[g], 0, 0, 0);
#pragma unroll
            for (int g = 0; g < 4; ++g) Red[wu][g][lane] = acc[g];
        }
        __syncthreads();
        if (ks == 0) {
#pragma unroll
            for (int g = 0; g < 4; ++g) acc[g] += Red[wu][g][lane];
            __hip_bfloat16* tp = (__hip_bfloat16*)&Tp[wu][0];
#pragma unroll
            for (int r = 0; r < 4; ++r) {
                const float pi = acc[0][r] + bg[0];
                const float pj = acc[1][r] + bg[1];
                const float pf = acc[2][r] + bg[2];
                const float po = acc[3][r] + bg[3];
                const float ai = sigmoidf_(pi);
                const float aj = tanhf_(pj);
                const float afv = sigmoidf_(pf);
                const float ao = sigmoidf_(po);
                const float cn = ai * aj + c4[r] * afv;
                c4[r] = cn;
                const float hn = ao * tanhf_(cn);
                if (t < Tn - 1) {
                    const int cp = (lk * 4 + r) * 2 + (l15 >> 3);
                    tp[swz16(cp) * 8 + (l15 & 7)] = __float2bfloat16(hn);
                } else {
                    out[(size_t)(cl * 16 + lk * 4 + r) * Hn + j * 64 + wu * 16 + l15] = hn;
                }
            }
            if (t < Tn - 1) {
                if (lane < 32) {
                    const bf16x8 val = Tp[wu][swz16(lane)];
                    const int clocal = (wu >> 1) * 64 + (lane >> 1)
                                     + 16 * ((wu & 1) * 2 + (lane & 1));
                    AfrH[swz(j * 128 + clocal)] = val;
                    char* dst = (char*)hbuf + (size_t)(((t + 1) & 1) * 16 + cl) * 8192
                              + j * 2048 + clocal * 16;
                    st16_llc(dst, val);
                }
                asm volatile("s_waitcnt vmcnt(0)" ::: "memory");
                if (lane == 0)
                    stdw_llc((char*)flags + (cl * 4 + j) * 16 + wu * 4, (uint32_t)(t + 1));
            }
        }
    }
}

// ===================== TIER 3: R3 fallback ==================================
__global__ void pack_w(const float* __restrict__ W, __hip_bfloat16* __restrict__ Wp) {
    int idx = blockIdx.x * 256 + threadIdx.x;
    int e = idx & 7, l = (idx >> 3) & 63, kb = (idx >> 9) & 15, nt = idx >> 13;
    int n = nt * 16 + (l & 15);
    int k = kb * 32 + (l >> 4) * 8 + e;
    Wp[idx] = __float2bfloat16(W[n * Kn + k]);
}

__global__ __launch_bounds__(1024, 4) void lstm_fused(
    const float* __restrict__ X, const float* __restrict__ bias,
    const __hip_bfloat16* __restrict__ Wp, float* __restrict__ out)
{
    constexpr int LDA = Kn + 8;
    __shared__ __hip_bfloat16 A[16][LDA];
    const int tid = threadIdx.x, wv = tid >> 6, lane = tid & 63;
    const int l15 = lane & 15, lk = lane >> 4, b0 = blockIdx.x * 16;
    const __hip_bfloat16* wp[4];
#pragma unroll
    for (int g = 0; g < 4; ++g) wp[g] = Wp + (size_t)(g * 16 + wv) * (16 * 512) + lane * 8;
    float bslot[4];
#pragma unroll
    for (int g = 0; g < 4; ++g) bslot[g] = bias[g * 256 + wv * 16 + l15];
    float c[4], h[4];
#pragma unroll
    for (int r = 0; r < 4; ++r) { c[r] = 0.f; h[r] = 0.f; }
    const float* xptr = X + ((size_t)(b0 + wv) * Tn) * In + lane * 4;
#pragma unroll 1
    for (int t = 0; t < Tn; ++t) {
        __syncthreads();
        {
            const float4 v = *(const float4*)(xptr + (size_t)t * In);
            __hip_bfloat16 tmp[4];
            tmp[0] = __float2bfloat16(v.x); tmp[1] = __float2bfloat16(v.y);
            tmp[2] = __float2bfloat16(v.z); tmp[3] = __float2bfloat16(v.w);
            *(ushort4*)&A[wv][lane * 4] = *(const ushort4*)tmp;
        }
#pragma unroll
        for (int r = 0; r < 4; ++r)
            A[lk * 4 + r][In + wv * 16 + l15] = __float2bfloat16(h[r]);
        __syncthreads();
        f32x4 acc[4];
#pragma unroll
        for (int g = 0; g < 4; ++g) acc[g] = f32x4{bslot[g], bslot[g], bslot[g], bslot[g]};
        bf16x8 wbuf[2][4];
#pragma unroll
        for (int g = 0; g < 4; ++g) wbuf[0][g] = *(const bf16x8*)(wp[g]);
#pragma unroll
        for (int kb = 0; kb < 16; ++kb) {
            const int cur = kb & 1;
            if (kb < 15) {
#pragma unroll
                for (int g = 0; g < 4; ++g)
                    wbuf[cur ^ 1][g] = *(const bf16x8*)(wp[g] + (kb + 1) * 512);
            }
            const bf16x8 a = *(const bf16x8*)&A[l15][kb * 32 + lk * 8];
#pragma unroll
            for (int g = 0; g < 4; ++g)
                acc[g] = __builtin_amdgcn_mfma_f32_16x16x32_bf16(a, wbuf[cur][g], acc[g], 0, 0, 0);
        }
#pragma unroll
        for (int r = 0; r < 4; ++r) {
            const float ai = sigmoidf_(acc[0][r]);
            const float aj = tanhf_(acc[1][r]);
            const float af = sigmoidf_(acc[2][r]);
            const float ao = sigmoidf_(acc[3][r]);
            const float cn = ai * aj + c[r] * af;
            c[r] = cn;
            h[r] = ao * tanhf_(cn);
            if (t == Tn - 1)
                out[(size_t)(b0 + lk * 4 + r) * Hn + wv * 16 + l15] = h[r];
        }
    }
}

} // namespace

extern "C" void kernel_launch(void* const* d_in, const int* in_sizes, int n_in,
                              void* d_out, int out_size, void* d_ws, size_t ws_size,
                              hipStream_t stream) {
    const float* X    = (const float*)d_in[0];   // [256][512][256] f32
    const float* W    = (const float*)d_in[1];   // [1024][512] f32
    const float* bias = (const float*)d_in[2];   // [1024] f32

    if (ws_size >= (size_t)0x180000) {
        // Tier 1: Wpf @0 (1MB), tagged hbuf @0x100000 (512KB)
        __hip_bfloat16* Wpf = (__hip_bfloat16*)d_ws;
        char*           hb  = (char*)d_ws + 0x100000;
        pack_w_tag<<<dim3(256), dim3(256), 0, stream>>>(W, Wpf, (unsigned long long*)hb);
        lstm_tag<<<dim3(64), dim3(512), 0, stream>>>(X, bias, Wpf, hb, (float*)d_out);
    } else if (ws_size >= (size_t)0x142000) {
        // Tier 2 (R9): Wpf @0, hbuf @0x100000 (256KB), flags @0x140000
        __hip_bfloat16* Wpf   = (__hip_bfloat16*)d_ws;
        __hip_bfloat16* hbuf  = (__hip_bfloat16*)((char*)d_ws + 0x100000);
        uint32_t*       flags = (uint32_t*)((char*)d_ws + 0x140000);
        pack_w_frag<<<dim3(256), dim3(256), 0, stream>>>(W, Wpf, flags);
        lstm_cluster<<<dim3(64), dim3(512), 0, stream>>>(X, bias, Wpf, hbuf, flags,
                                                         (float*)d_out);
    } else {
        __hip_bfloat16* Wp = (__hip_bfloat16*)d_ws;
        pack_w<<<dim3(2048), dim3(256), 0, stream>>>(W, Wp);
        lstm_fused<<<dim3(16), dim3(1024), 0, stream>>>(X, bias, Wp, (float*)d_out);
    }
}

// Round 11
// 1107.718 us; speedup vs baseline: 5.1339x; 1.3668x over previous
//
#include <hip/hip_runtime.h>
#include <hip/hip_bf16.h>
#include <stdint.h>

namespace {

constexpr int Tn = 512, In = 256, Hn = 256, Kn = 512;

typedef __attribute__((ext_vector_type(8))) short bf16x8;
typedef __attribute__((ext_vector_type(4))) float f32x4;
typedef __attribute__((ext_vector_type(4))) unsigned int u32x4;

__device__ __forceinline__ float sigmoidf_(float x) { return 1.f / (1.f + __expf(-x)); }
__device__ __forceinline__ float tanhf_(float x)    { return 2.f / (1.f + __expf(-2.f * x)) - 1.f; }

// A-tile chunk swizzle (R5-validated)
__device__ __forceinline__ int swz(int c) { return c ^ ((c >> 4) & 15); }
// transpose-patch swizzle (tier-2 only)
__device__ __forceinline__ int swz16(int c) { return c ^ (((c >> 3) & 3) << 1); }

// LDS-only barrier: no vmcnt drain (poll tails / fire-and-forget exports may
// stay in flight). Single asm block so no memory op can cross either side.
__device__ __forceinline__ void bar_lds() {
    asm volatile("s_waitcnt lgkmcnt(0)\n\ts_barrier" ::: "memory");
}

// sc1 = agent/LLC-coherent ops (R5-proven prompt cross-WG channel)
__device__ __forceinline__ void st16_llc(void* p, bf16x8 v) {
    asm volatile("global_store_dwordx4 %0, %1, off sc1" :: "v"(p), "v"(v) : "memory");
}
__device__ __forceinline__ bf16x8 ld16_llc(const void* p) {
    bf16x8 r;
    asm volatile("global_load_dwordx4 %0, %1, off sc1" : "=v"(r) : "v"(p) : "memory");
    return r;
}
__device__ __forceinline__ u32x4 ld16u_llc(const void* p) {
    u32x4 r;
    asm volatile("global_load_dwordx4 %0, %1, off sc1" : "=v"(r) : "v"(p) : "memory");
    return r;
}
__device__ __forceinline__ u32x4 ldflags_llc(const void* p) {
    u32x4 r;
    asm volatile("global_load_dwordx4 %0, %1, off sc1\n\ts_waitcnt vmcnt(0)"
                 : "=v"(r) : "v"(p) : "memory");
    return r;
}
__device__ __forceinline__ void stdw_llc(void* p, uint32_t v) {
    asm volatile("global_store_dword %0, %1, off sc1" :: "v"(p), "v"(v) : "memory");
}

// tag check: 8 dwords, hi-u16 must all equal want (wt = want<<16)
__device__ __forceinline__ bool tags8(u32x4 a, u32x4 b, uint32_t wt) {
    uint32_t d = (a.x ^ wt) | (a.y ^ wt) | (a.z ^ wt) | (a.w ^ wt)
               | (b.x ^ wt) | (b.y ^ wt) | (b.z ^ wt) | (b.w ^ wt);
    return (d & 0xFFFF0000u) == 0u;
}
__device__ __forceinline__ bf16x8 pack8(u32x4 a, u32x4 b) {
    union { uint32_t u[4]; bf16x8 v; } r;
    r.u[0] = (a.x & 0xFFFFu) | (a.y << 16);
    r.u[1] = (a.z & 0xFFFFu) | (a.w << 16);
    r.u[2] = (b.x & 0xFFFFu) | (b.y << 16);
    r.u[3] = (b.z & 0xFFFFu) | (b.w << 16);
    return r.v;
}

// ===================== TIER 1: tag-in-data, role-merged =====================
// 64 WGs: wg = cl + 16*j. Cluster cl owns batch [16cl,+16); member j owns units [64j,+64).
// 8 waves: w8 = ks*4 + wu.
//   ks=0 wave wu (pre-B2): x-GEMM(t) kb0..7 -> Red[wu]; stage x(t+1).
//   ks=1 wave wu (pre-B2): poll+import mate wu's h(t-1) (wu==j: nothing).
//   post-B2, ks=1: h-GEMM kb8..15 + Red -> gates -> export (tagged dwords).
//   post-B3, ks=1: own-member h -> AfrH (ordered vs next h-GEMM by B2(t+1)).
// Barriers are LDS-only (bar_lds): no vmcnt drain on the critical path.

__global__ void pack_w_tag(const float* __restrict__ W, __hip_bfloat16* __restrict__ Wpf,
                           unsigned long long* __restrict__ hz) {
    int idx  = blockIdx.x * 256 + threadIdx.x;   // 65536 total
    int lane = idx & 63;
    int kb   = (idx >> 6) & 15;
    int nt2  = idx >> 10;
    int g = nt2 & 3, wu = (nt2 >> 2) & 3, jj = nt2 >> 4;
    int row = g * 256 + jj * 64 + wu * 16 + (lane & 15);
    int k0  = kb * 32 + (lane >> 4) * 8;
    const float* src = W + (size_t)row * Kn + k0;
    union { __hip_bfloat16 h[8]; bf16x8 v; } u;
#pragma unroll
    for (int e = 0; e < 8; ++e) u.h[e] = __float2bfloat16(src[e]);
    *(bf16x8*)(Wpf + (size_t)idx * 8) = u.v;
    // zero tagged hbuf (512KB) EVERY launch (stale tags from prior replay)
    hz[idx] = 0ULL;
}

__global__ __launch_bounds__(512, 2) void lstm_tag(
    const float* __restrict__ X, const float* __restrict__ bias,
    const __hip_bfloat16* __restrict__ Wpf, char* __restrict__ hbuf,
    float* __restrict__ out)
{
    __shared__ bf16x8 AfrX[2][512];    // 16 KB double-buffered x frags (kb 0..7)
    __shared__ bf16x8 AfrH[512];       // 8 KB h frags (kb 8..15)
    __shared__ f32x4 Red[4][4][64];    // 16 KB x-GEMM partials (ks=0 -> ks=1)

    const int tid = threadIdx.x, lane = tid & 63, w8 = tid >> 6;
    const int wu = w8 & 3, ks = w8 >> 2;
    const int l15 = lane & 15, lk = lane >> 4;
    const int wg = blockIdx.x, cl = wg & 15, j = wg >> 4;

    // ---- resident weights: 32 frags / lane (ks picks the K-half) ----
    bf16x8 wf[4][8];
#pragma unroll
    for (int g = 0; g < 4; ++g)
#pragma unroll
        for (int i = 0; i < 8; ++i) {
            const int nt2 = (j * 4 + wu) * 4 + g, kb = ks * 8 + i;
            wf[g][i] = *(const bf16x8*)(Wpf + ((size_t)(nt2 * 16 + kb) * 64 + lane) * 8);
        }
    float bg[4];
#pragma unroll
    for (int g = 0; g < 4; ++g) bg[g] = bias[g * 256 + j * 64 + wu * 16 + l15];

    float c4[4] = {0.f, 0.f, 0.f, 0.f};   // live in ks=1 waves

    // zero h region (h(-1) = 0)
    {
        const bf16x8 z = {};
        AfrH[tid] = z;
    }

    // ---- prologue: stage x(0); prefetch x(1) ----
    const int b = wu * 4 + lk;
    const float* xbase = X + (size_t)(cl * 16 + b) * Tn * In;
    float4 xp[4];
    if (ks == 0) {
#pragma unroll
        for (int cc = 0; cc < 2; ++cc) {
            const int o8 = l15 + cc * 16;
            const float4 v0 = *(const float4*)(xbase + o8 * 8);
            const float4 v1 = *(const float4*)(xbase + o8 * 8 + 4);
            union { __hip_bfloat16 h[8]; bf16x8 v; } u;
            u.h[0] = __float2bfloat16(v0.x); u.h[1] = __float2bfloat16(v0.y);
            u.h[2] = __float2bfloat16(v0.z); u.h[3] = __float2bfloat16(v0.w);
            u.h[4] = __float2bfloat16(v1.x); u.h[5] = __float2bfloat16(v1.y);
            u.h[6] = __float2bfloat16(v1.z); u.h[7] = __float2bfloat16(v1.w);
            AfrX[0][swz(b + 16 * o8)] = u.v;
        }
#pragma unroll
        for (int cc = 0; cc < 2; ++cc) {
            const int o8 = l15 + cc * 16;
            xp[cc * 2]     = *(const float4*)(xbase + In + o8 * 8);
            xp[cc * 2 + 1] = *(const float4*)(xbase + In + o8 * 8 + 4);
        }
    }
    __syncthreads();   // prologue barrier (full semantics fine here)

#pragma unroll 1
    for (int t = 0; t < Tn; ++t) {
        if (ks == 0) {
            // ---- x-GEMM(t) -> Red; stage x(t+1). All off the critical path ----
            f32x4 acc[4] = {};
            bf16x8 af[8];
#pragma unroll
            for (int i = 0; i < 8; ++i)
                af[i] = AfrX[t & 1][swz(i * 64 + lane)];
#pragma unroll
            for (int i = 0; i < 8; ++i)
#pragma unroll
                for (int g = 0; g < 4; ++g)
                    acc[g] = __builtin_amdgcn_mfma_f32_16x16x32_bf16(af[i], wf[g][i], acc[g], 0, 0, 0);
#pragma unroll
            for (int g = 0; g < 4; ++g) Red[wu][g][lane] = acc[g];
            if (t + 1 < Tn) {
#pragma unroll
                for (int cc = 0; cc < 2; ++cc) {
                    const int o8 = l15 + cc * 16;
                    union { __hip_bfloat16 h[8]; bf16x8 v; } u;
                    u.h[0] = __float2bfloat16(xp[cc * 2].x); u.h[1] = __float2bfloat16(xp[cc * 2].y);
                    u.h[2] = __float2bfloat16(xp[cc * 2].z); u.h[3] = __float2bfloat16(xp[cc * 2].w);
                    u.h[4] = __float2bfloat16(xp[cc * 2 + 1].x); u.h[5] = __float2bfloat16(xp[cc * 2 + 1].y);
                    u.h[6] = __float2bfloat16(xp[cc * 2 + 1].z); u.h[7] = __float2bfloat16(xp[cc * 2 + 1].w);
                    AfrX[(t + 1) & 1][swz(b + 16 * o8)] = u.v;
                }
            }
        } else if (t > 0 && wu != j) {
            // ---- import mate wu's h(t-1): poll the tagged data (R10-proven) ----
            const char* ib = hbuf + (size_t)(((cl * 4 + wu) * 2 + (t & 1)) * 4096)
                           + (lane & 15) * 256 + (lane >> 4) * 32;
            const uint32_t wt = ((uint32_t)t) << 16;
            u32x4 A0 = {}, A1 = {}, B0 = {}, B1 = {};
            bool f0 = false, f1 = false;
            int g2 = 0;
            for (;;) {
                if (!f0) { A0 = ld16u_llc(ib);       A1 = ld16u_llc(ib + 16); }
                if (!f1) { B0 = ld16u_llc(ib + 128); B1 = ld16u_llc(ib + 144); }
                asm volatile("s_waitcnt vmcnt(0)" ::: "memory");
                f0 = f0 || tags8(A0, A1, wt);
                f1 = f1 || tags8(B0, B1, wt);
                if (__all(f0 && f1) || ++g2 >= 1024) break;
            }
            __builtin_amdgcn_sched_barrier(0);
            AfrH[swz(wu * 128 + lane)]      = pack8(A0, A1);
            AfrH[swz(wu * 128 + 64 + lane)] = pack8(B0, B1);
        }
        bar_lds();   // B2: AfrH(t-1) complete, Red(t) complete, AfrX(t+1) staged

        uint16_t hb[4];
        if (ks == 0) {
            // x(t+2) prefetch (compiler-tracked loads; hides under h-GEMM+gates)
            if (t + 2 < Tn) {
                const float* xs = xbase + (size_t)(t + 2) * In;
#pragma unroll
                for (int cc = 0; cc < 2; ++cc) {
                    const int o8 = l15 + cc * 16;
                    xp[cc * 2]     = *(const float4*)(xs + o8 * 8);
                    xp[cc * 2 + 1] = *(const float4*)(xs + o8 * 8 + 4);
                }
            }
        } else {
            // ---- h-GEMM + reduce + gates + export, all in this wave ----
            f32x4 acc[4] = {};
            bf16x8 af[8];
#pragma unroll
            for (int i = 0; i < 8; ++i)
                af[i] = AfrH[swz(i * 64 + lane)];
#pragma unroll
            for (int i = 0; i < 8; ++i)
#pragma unroll
                for (int g = 0; g < 4; ++g)
                    acc[g] = __builtin_amdgcn_mfma_f32_16x16x32_bf16(af[i], wf[g][i], acc[g], 0, 0, 0);
#pragma unroll
            for (int g = 0; g < 4; ++g) acc[g] += Red[wu][g][lane];
#pragma unroll
            for (int r = 0; r < 4; ++r) {
                const float pi = acc[0][r] + bg[0];
                const float pj = acc[1][r] + bg[1];
                const float pf = acc[2][r] + bg[2];
                const float po = acc[3][r] + bg[3];
                const float ai = sigmoidf_(pi);
                const float aj = tanhf_(pj);
                const float afv = sigmoidf_(pf);
                const float ao = sigmoidf_(po);
                const float cn = ai * aj + c4[r] * afv;
                c4[r] = cn;
                const float hn = ao * tanhf_(cn);
                if (t < Tn - 1) {
                    union { __hip_bfloat16 bh; uint16_t u; } cv;
                    cv.bh = __float2bfloat16(hn);
                    hb[r] = cv.u;
                } else {
                    out[(size_t)(cl * 16 + lk * 4 + r) * Hn + j * 64 + wu * 16 + l15] = hn;
                }
            }
            if (t < Tn - 1) {
                // drain own old stores (same-dword ordering across parity reuse),
                // then fire-and-forget tagged exports -- earliest possible issue
                asm volatile("s_waitcnt vmcnt(0)" ::: "memory");
                char* eb = hbuf + (size_t)(((cl * 4 + j) * 2 + ((t + 1) & 1)) * 4096);
                const uint32_t tagw = ((uint32_t)(t + 1)) << 16;
#pragma unroll
                for (int r = 0; r < 4; ++r)
                    stdw_llc(eb + (((lk * 4 + r) * 64 + wu * 16 + l15) << 2),
                             (uint32_t)hb[r] | tagw);
            }
        }
        bar_lds();   // B3: h-GEMM AfrH/Red reads done -> next-step overwrites safe

        // own-member h -> AfrH AFTER B3 (other ks=1 waves' h-GEMM reads of slice j
        // finished pre-B3; next readers are post-B2(t+1), ordered by bar_lds)
        if (ks == 1 && t < Tn - 1) {
#pragma unroll
            for (int r = 0; r < 4; ++r) {
                const int c = j * 128 + (wu >> 1) * 64
                            + ((wu & 1) * 2 + (l15 >> 3)) * 16 + lk * 4 + r;
                *(uint16_t*)((char*)AfrH + swz(c) * 16 + (l15 & 7) * 2) = hb[r];
            }
        }
    }
}

// ===================== TIER 2: R9 flag protocol (proven 1724us) =============
__global__ void pack_w_frag(const float* __restrict__ W, __hip_bfloat16* __restrict__ Wpf,
                            uint32_t* __restrict__ flags) {
    int idx  = blockIdx.x * 256 + threadIdx.x;
    int lane = idx & 63;
    int kb   = (idx >> 6) & 15;
    int nt2  = idx >> 10;
    int g = nt2 & 3, wu = (nt2 >> 2) & 3, jj = nt2 >> 4;
    int row = g * 256 + jj * 64 + wu * 16 + (lane & 15);
    int k0  = kb * 32 + (lane >> 4) * 8;
    const float* src = W + (size_t)row * Kn + k0;
    union { __hip_bfloat16 h[8]; bf16x8 v; } u;
#pragma unroll
    for (int e = 0; e < 8; ++e) u.h[e] = __float2bfloat16(src[e]);
    *(bf16x8*)(Wpf + (size_t)idx * 8) = u.v;
    if (blockIdx.x == 0 && threadIdx.x < 256)
        flags[threadIdx.x] = 0u;
}

__global__ __launch_bounds__(512, 2) void lstm_cluster(
    const float* __restrict__ X, const float* __restrict__ bias,
    const __hip_bfloat16* __restrict__ Wpf, __hip_bfloat16* __restrict__ hbuf,
    uint32_t* __restrict__ flags, float* __restrict__ out)
{
    __shared__ bf16x8 AfrX[2][512];
    __shared__ bf16x8 AfrH[512];
    __shared__ f32x4 Red[4][4][64];
    __shared__ bf16x8 Tp[4][32];

    const int tid = threadIdx.x, lane = tid & 63, w8 = tid >> 6;
    const int wu = w8 & 3, ks = w8 >> 2;
    const int l15 = lane & 15, lk = lane >> 4;
    const int wg = blockIdx.x, cl = wg & 15, j = wg >> 4;

    bf16x8 wf[4][8];
#pragma unroll
    for (int g = 0; g < 4; ++g)
#pragma unroll
        for (int i = 0; i < 8; ++i) {
            const int nt2 = (j * 4 + wu) * 4 + g, kb = ks * 8 + i;
            wf[g][i] = *(const bf16x8*)(Wpf + ((size_t)(nt2 * 16 + kb) * 64 + lane) * 8);
        }
    float bg[4];
#pragma unroll
    for (int g = 0; g < 4; ++g) bg[g] = bias[g * 256 + j * 64 + wu * 16 + l15];
    float c4[4] = {0.f, 0.f, 0.f, 0.f};
    {
        const bf16x8 z = {};
        AfrH[tid] = z;
    }
    const int b = wu * 4 + lk;
    const float* xbase = X + (size_t)(cl * 16 + b) * Tn * In;
    float4 xp[4];
    if (ks == 0) {
#pragma unroll
        for (int cc = 0; cc < 2; ++cc) {
            const int o8 = l15 + cc * 16;
            const float4 v0 = *(const float4*)(xbase + o8 * 8);
            const float4 v1 = *(const float4*)(xbase + o8 * 8 + 4);
            union { __hip_bfloat16 h[8]; bf16x8 v; } u;
            u.h[0] = __float2bfloat16(v0.x); u.h[1] = __float2bfloat16(v0.y);
            u.h[2] = __float2bfloat16(v0.z); u.h[3] = __float2bfloat16(v0.w);
            u.h[4] = __float2bfloat16(v1.x); u.h[5] = __float2bfloat16(v1.y);
            u.h[6] = __float2bfloat16(v1.z); u.h[7] = __float2bfloat16(v1.w);
            AfrX[0][swz(b + 16 * o8)] = u.v;
        }
#pragma unroll
        for (int cc = 0; cc < 2; ++cc) {
            const int o8 = l15 + cc * 16;
            xp[cc * 2]     = *(const float4*)(xbase + In + o8 * 8);
            xp[cc * 2 + 1] = *(const float4*)(xbase + In + o8 * 8 + 4);
        }
    }
    __syncthreads();
#pragma unroll 1
    for (int t = 0; t < Tn; ++t) {
        f32x4 acc[4] = {};
        if (ks == 0) {
            bf16x8 af[8];
#pragma unroll
            for (int i = 0; i < 8; ++i)
                af[i] = AfrX[t & 1][swz(i * 64 + lane)];
#pragma unroll
            for (int i = 0; i < 8; ++i)
#pragma unroll
                for (int g = 0; g < 4; ++g)
                    acc[g] = __builtin_amdgcn_mfma_f32_16x16x32_bf16(af[i], wf[g][i], acc[g], 0, 0, 0);
            if (t + 1 < Tn) {
#pragma unroll
                for (int cc = 0; cc < 2; ++cc) {
                    const int o8 = l15 + cc * 16;
                    union { __hip_bfloat16 h[8]; bf16x8 v; } u;
                    u.h[0] = __float2bfloat16(xp[cc * 2].x); u.h[1] = __float2bfloat16(xp[cc * 2].y);
                    u.h[2] = __float2bfloat16(xp[cc * 2].z); u.h[3] = __float2bfloat16(xp[cc * 2].w);
                    u.h[4] = __float2bfloat16(xp[cc * 2 + 1].x); u.h[5] = __float2bfloat16(xp[cc * 2 + 1].y);
                    u.h[6] = __float2bfloat16(xp[cc * 2 + 1].z); u.h[7] = __float2bfloat16(xp[cc * 2 + 1].w);
                    AfrX[(t + 1) & 1][swz(b + 16 * o8)] = u.v;
                }
            }
        } else if (t > 0 && wu != j) {
            const char* fl = (const char*)flags + (cl * 4 + wu) * 16;
            uint32_t g2 = 0;
            for (;;) {
                u32x4 f = ldflags_llc(fl);
                uint32_t mn = f.x < f.y ? f.x : f.y;
                const uint32_t mn2 = f.z < f.w ? f.z : f.w;
                if (mn2 < mn) mn = mn2;
                if (mn >= (uint32_t)t || ++g2 >= (1u << 12)) break;
            }
            const char* src = (const char*)hbuf + (size_t)((t & 1) * 16 + cl) * 8192
                            + wu * 2048 + lane * 16;
            const bf16x8 r0 = ld16_llc(src);
            const bf16x8 r1 = ld16_llc(src + 1024);
            asm volatile("s_waitcnt vmcnt(0)" ::: "memory");
            __builtin_amdgcn_sched_barrier(0);
            AfrH[swz(wu * 128 + lane)]      = r0;
            AfrH[swz(wu * 128 + lane + 64)] = r1;
        }
        __syncthreads();
        if (ks == 0) {
            if (t + 2 < Tn) {
                const float* xs = xbase + (size_t)(t + 2) * In;
#pragma unroll
                for (int cc = 0; cc < 2; ++cc) {
                    const int o8 = l15 + cc * 16;
                    xp[cc * 2]     = *(const float4*)(xs + o8 * 8);
                    xp[cc * 2 + 1] = *(const float4*)(xs + o8 * 8 + 4);
                }
            }
        } else {
            bf16x8 af[8];
#pragma unroll
            for (int i = 0; i < 8; ++i)
                af[i] = AfrH[swz(i * 64 + lane)];
#pragma unroll
            for (int i = 0; i < 8; ++i)
#pragma unroll
                for (int g = 0; g < 4; ++g)
                    acc[g] = __builtin_amdgcn_mfma_f32_16x16x32_bf16(af[i], wf[g][i], acc[g], 0, 0, 0);
#pragma unroll
            for (int g = 0; g < 4; ++g) Red[wu][g][lane] = acc[g];
        }
        __syncthreads();
        if (ks == 0) {
#pragma unroll
            for (int g = 0; g < 4; ++g) acc[g] += Red[wu][g][lane];
            __hip_bfloat16* tp = (__hip_bfloat16*)&Tp[wu][0];
#pragma unroll
            for (int r = 0; r < 4; ++r) {
                const float pi = acc[0][r] + bg[0];
                const float pj = acc[1][r] + bg[1];
                const float pf = acc[2][r] + bg[2];
                const float po = acc[3][r] + bg[3];
                const float ai = sigmoidf_(pi);
                const float aj = tanhf_(pj);
                const float afv = sigmoidf_(pf);
                const float ao = sigmoidf_(po);
                const float cn = ai * aj + c4[r] * afv;
                c4[r] = cn;
                const float hn = ao * tanhf_(cn);
                if (t < Tn - 1) {
                    const int cp = (lk * 4 + r) * 2 + (l15 >> 3);
                    tp[swz16(cp) * 8 + (l15 & 7)] = __float2bfloat16(hn);
                } else {
                    out[(size_t)(cl * 16 + lk * 4 + r) * Hn + j * 64 + wu * 16 + l15] = hn;
                }
            }
            if (t < Tn - 1) {
                if (lane < 32) {
                    const bf16x8 val = Tp[wu][swz16(lane)];
                    const int clocal = (wu >> 1) * 64 + (lane >> 1)
                                     + 16 * ((wu & 1) * 2 + (lane & 1));
                    AfrH[swz(j * 128 + clocal)] = val;
                    char* dst = (char*)hbuf + (size_t)(((t + 1) & 1) * 16 + cl) * 8192
                              + j * 2048 + clocal * 16;
                    st16_llc(dst, val);
                }
                asm volatile("s_waitcnt vmcnt(0)" ::: "memory");
                if (lane == 0)
                    stdw_llc((char*)flags + (cl * 4 + j) * 16 + wu * 4, (uint32_t)(t + 1));
            }
        }
    }
}

// ===================== TIER 3: R3 fallback ==================================
__global__ void pack_w(const float* __restrict__ W, __hip_bfloat16* __restrict__ Wp) {
    int idx = blockIdx.x * 256 + threadIdx.x;
    int e = idx & 7, l = (idx >> 3) & 63, kb = (idx >> 9) & 15, nt = idx >> 13;
    int n = nt * 16 + (l & 15);
    int k = kb * 32 + (l >> 4) * 8 + e;
    Wp[idx] = __float2bfloat16(W[n * Kn + k]);
}

__global__ __launch_bounds__(1024, 4) void lstm_fused(
    const float* __restrict__ X, const float* __restrict__ bias,
    const __hip_bfloat16* __restrict__ Wp, float* __restrict__ out)
{
    constexpr int LDA = Kn + 8;
    __shared__ __hip_bfloat16 A[16][LDA];
    const int tid = threadIdx.x, wv = tid >> 6, lane = tid & 63;
    const int l15 = lane & 15, lk = lane >> 4, b0 = blockIdx.x * 16;
    const __hip_bfloat16* wp[4];
#pragma unroll
    for (int g = 0; g < 4; ++g) wp[g] = Wp + (size_t)(g * 16 + wv) * (16 * 512) + lane * 8;
    float bslot[4];
#pragma unroll
    for (int g = 0; g < 4; ++g) bslot[g] = bias[g * 256 + wv * 16 + l15];
    float c[4], h[4];
#pragma unroll
    for (int r = 0; r < 4; ++r) { c[r] = 0.f; h[r] = 0.f; }
    const float* xptr = X + ((size_t)(b0 + wv) * Tn) * In + lane * 4;
#pragma unroll 1
    for (int t = 0; t < Tn; ++t) {
        __syncthreads();
        {
            const float4 v = *(const float4*)(xptr + (size_t)t * In);
            __hip_bfloat16 tmp[4];
            tmp[0] = __float2bfloat16(v.x); tmp[1] = __float2bfloat16(v.y);
            tmp[2] = __float2bfloat16(v.z); tmp[3] = __float2bfloat16(v.w);
            *(ushort4*)&A[wv][lane * 4] = *(const ushort4*)tmp;
        }
#pragma unroll
        for (int r = 0; r < 4; ++r)
            A[lk * 4 + r][In + wv * 16 + l15] = __float2bfloat16(h[r]);
        __syncthreads();
        f32x4 acc[4];
#pragma unroll
        for (int g = 0; g < 4; ++g) acc[g] = f32x4{bslot[g], bslot[g], bslot[g], bslot[g]};
        bf16x8 wbuf[2][4];
#pragma unroll
        for (int g = 0; g < 4; ++g) wbuf[0][g] = *(const bf16x8*)(wp[g]);
#pragma unroll
        for (int kb = 0; kb < 16; ++kb) {
            const int cur = kb & 1;
            if (kb < 15) {
#pragma unroll
                for (int g = 0; g < 4; ++g)
                    wbuf[cur ^ 1][g] = *(const bf16x8*)(wp[g] + (kb + 1) * 512);
            }
            const bf16x8 a = *(const bf16x8*)&A[l15][kb * 32 + lk * 8];
#pragma unroll
            for (int g = 0; g < 4; ++g)
                acc[g] = __builtin_amdgcn_mfma_f32_16x16x32_bf16(a, wbuf[cur][g], acc[g], 0, 0, 0);
        }
#pragma unroll
        for (int r = 0; r < 4; ++r) {
            const float ai = sigmoidf_(acc[0][r]);
            const float aj = tanhf_(acc[1][r]);
            const float af = sigmoidf_(acc[2][r]);
            const float ao = sigmoidf_(acc[3][r]);
            const float cn = ai * aj + c[r] * af;
            c[r] = cn;
            h[r] = ao * tanhf_(cn);
            if (t == Tn - 1)
                out[(size_t)(b0 + lk * 4 + r) * Hn + wv * 16 + l15] = h[r];
        }
    }
}

} // namespace

extern "C" void kernel_launch(void* const* d_in, const int* in_sizes, int n_in,
                              void* d_out, int out_size, void* d_ws, size_t ws_size,
                              hipStream_t stream) {
    const float* X    = (const float*)d_in[0];   // [256][512][256] f32
    const float* W    = (const float*)d_in[1];   // [1024][512] f32
    const float* bias = (const float*)d_in[2];   // [1024] f32

    if (ws_size >= (size_t)0x180000) {
        // Tier 1: Wpf @0 (1MB), tagged hbuf @0x100000 (512KB)
        __hip_bfloat16* Wpf = (__hip_bfloat16*)d_ws;
        char*           hb  = (char*)d_ws + 0x100000;
        pack_w_tag<<<dim3(256), dim3(256), 0, stream>>>(W, Wpf, (unsigned long long*)hb);
        lstm_tag<<<dim3(64), dim3(512), 0, stream>>>(X, bias, Wpf, hb, (float*)d_out);
    } else if (ws_size >= (size_t)0x142000) {
        // Tier 2 (R9): Wpf @0, hbuf @0x100000 (256KB), flags @0x140000
        __hip_bfloat16* Wpf   = (__hip_bfloat16*)d_ws;
        __hip_bfloat16* hbuf  = (__hip_bfloat16*)((char*)d_ws + 0x100000);
        uint32_t*       flags = (uint32_t*)((char*)d_ws + 0x140000);
        pack_w_frag<<<dim3(256), dim3(256), 0, stream>>>(W, Wpf, flags);
        lstm_cluster<<<dim3(64), dim3(512), 0, stream>>>(X, bias, Wpf, hbuf, flags,
                                                         (float*)d_out);
    } else {
        __hip_bfloat16* Wp = (__hip_bfloat16*)d_ws;
        pack_w<<<dim3(2048), dim3(256), 0, stream>>>(W, Wp);
        lstm_fused<<<dim3(16), dim3(1024), 0, stream>>>(X, bias, Wp, (float*)d_out);
    }
}